// Round 12
// baseline (315.255 us; speedup 1.0000x reference)
//
#include <hip/hip_runtime.h>
#include <hip/hip_bf16.h>

#define Bc 4
#define Sc 2048
#define Ec 1024
#define Hc 16
#define Dc 64

typedef __bf16 bf16_t;
typedef __bf16 bf16x4 __attribute__((ext_vector_type(4)));
typedef __bf16 bf16x8 __attribute__((ext_vector_type(8)));
typedef float f32x4 __attribute__((ext_vector_type(4)));

extern "C" __device__ float __ocml_native_exp2_f32(float);  // bare v_exp_f32

__device__ __forceinline__ f32x4 mfma16(bf16x8 a, bf16x8 b, f32x4 c) {
    return __builtin_amdgcn_mfma_f32_16x16x32_bf16(a, b, c, 0, 0, 0);
}

// async global->LDS, 16B per lane; LDS dst = wave-uniform base + lane*16
__device__ __forceinline__ void gload16(const bf16_t* g, bf16_t* l) {
    __builtin_amdgcn_global_load_lds(
        (const __attribute__((address_space(1))) unsigned int*)g,
        (__attribute__((address_space(3))) unsigned int*)l, 16, 0, 0);
}

#define FENCE asm volatile("" ::: "memory")
#define BARRIER do { FENCE; __builtin_amdgcn_s_barrier(); FENCE; } while (0)

// ---------------------------------------------------------------------------
// f32 -> bf16 elementwise convert (vectorized)
// ---------------------------------------------------------------------------
__global__ __launch_bounds__(256)
void cvt_bf16(const float* __restrict__ in, bf16_t* __restrict__ out, int n4)
{
    int i = blockIdx.x * 256 + threadIdx.x;
    if (i >= n4) return;
    float4 v = ((const float4*)in)[i];
    alignas(8) bf16_t o[4];
    o[0] = (bf16_t)v.x; o[1] = (bf16_t)v.y; o[2] = (bf16_t)v.z; o[3] = (bf16_t)v.w;
    ((uint2*)out)[i] = *(uint2*)o;
}

// ---------------------------------------------------------------------------
// W[K][N] f32 -> Wt[N][K] bf16, 64x64 LDS tiles
// ---------------------------------------------------------------------------
__global__ __launch_bounds__(256)
void transpose_w(const float* __restrict__ W, bf16_t* __restrict__ Wt, int K, int N)
{
    __shared__ float T[64][65];
    const int kt = blockIdx.y, nt = blockIdx.x;
    const int r = threadIdx.x >> 4;          // 0..15
    const int c = (threadIdx.x & 15) * 4;    // 0..60
    #pragma unroll
    for (int p = 0; p < 4; p++) {
        float4 v = *(const float4*)(W + (size_t)(kt*64 + r + p*16)*N + nt*64 + c);
        T[r + p*16][c] = v.x; T[r + p*16][c+1] = v.y;
        T[r + p*16][c+2] = v.z; T[r + p*16][c+3] = v.w;
    }
    __syncthreads();
    #pragma unroll
    for (int p = 0; p < 4; p++) {
        int n = nt*64 + r + p*16;
        alignas(8) bf16_t tmp[4];
        #pragma unroll
        for (int j = 0; j < 4; j++) tmp[j] = (bf16_t)T[c + j][r + p*16];
        *(uint2*)(Wt + (size_t)n*K + kt*64 + c) = *(uint2*)tmp;
    }
}

// ---------------------------------------------------------------------------
// V slice of qkv [token][3E] -> Vt[bh][d][s], natural key order.
// ---------------------------------------------------------------------------
__global__ __launch_bounds__(256)
void transpose_v(const bf16_t* __restrict__ qkv, bf16_t* __restrict__ vt)
{
    __shared__ bf16_t T[64][72];
    const int bh = blockIdx.y, st = blockIdx.x;
    const int b = bh >> 4, h = bh & 15;
    const int sr = threadIdx.x >> 3;         // 0..31
    const int dc = (threadIdx.x & 7) * 8;    // 0..56
    #pragma unroll
    for (int p = 0; p < 2; p++) {
        const bf16_t* src = qkv + (size_t)(b*Sc + st*64 + sr + p*32)*(3*Ec) + 2*Ec + h*Dc + dc;
        *(uint4*)&T[sr + p*32][dc] = *(const uint4*)src;
    }
    __syncthreads();
    const int dr = threadIdx.x >> 3;
    const int sc2 = (threadIdx.x & 7) * 8;
    #pragma unroll
    for (int p = 0; p < 2; p++) {
        alignas(16) bf16_t tmp[8];
        #pragma unroll
        for (int j = 0; j < 8; j++)
            tmp[j] = T[sc2 + j][dr + p*32];
        *(uint4*)(vt + (size_t)bh*Dc*Sc + (size_t)(dr + p*32)*Sc + st*64 + sc2) = *(uint4*)tmp;
    }
}

// ---------------------------------------------------------------------------
// gemm3b: C[M,N] = A[M,K]@Bt[N,K]^T + bias.
// Triple-buffered counted-vmcnt schedule: BM=128 BN=256 BK=64, 8 waves,
// per-wave 64x64 out (32 MFMA/phase), LDS 144KB, vmcnt(6) per phase,
// chunk-XOR swizzle, XCD-aware block swizzle. (R5: both GEMMs < 74us.)
// ---------------------------------------------------------------------------
template<int OUT_IS_F32>
__global__ __launch_bounds__(512)
void gemm3b(const bf16_t* __restrict__ A, const bf16_t* __restrict__ Bt,
            const float* __restrict__ biasp, void* __restrict__ Cp,
            int M, int N, int K)
{
    // per buffer: A rows [0,128), B rows [128,384), 64 elems/row
    __shared__ bf16_t LS[3][384*64];

    const int tid  = threadIdx.x;
    const int wave = tid >> 6;          // 0..7
    const int lane = tid & 63;
    const int quad = lane >> 4;
    const int l16  = lane & 15;
    const int wm   = (wave >> 2) * 64;  // 2 M-groups x 64 rows
    const int wn   = (wave & 3) * 64;   // 4 N-groups x 64 cols

    // XCD-aware swizzle (both grids are multiples of 8)
    const int nwg = gridDim.x * gridDim.y;
    const int bid = blockIdx.y * gridDim.x + blockIdx.x;
    const int cpx = nwg >> 3;
    const int swz = (bid & 7) * cpx + (bid >> 3);
    const int nbx = N >> 8;
    const int m0  = (swz / nbx) * 128;
    const int n0  = (swz % nbx) * 256;

    const int NT = K >> 6;

    // staging: each wave stages 8 rows/chunk; src col pre-swizzled so linear
    // LDS dest ends up chunk-XOR-permuted: phys_chunk = log_chunk ^ ((row>>1)&7)
    const int srow = lane >> 3;                                  // 0..7
    const int sch  = (lane & 7) ^ ((wave*4 + (lane >> 4)) & 7);  // logical 16B chunk
    const bf16_t* aSrc = A  + (size_t)(m0 + wave*8 + srow)*K + sch*8;
    const bf16_t* bSrc = Bt + (size_t)(n0 + wave*8 + srow)*K + sch*8;

    const int fsw = (l16 >> 1) & 7;   // read-side swizzle (same involution)

    f32x4 acc[4][4] = {};

    auto stage = [&](int bi, int t) {   // 6 gload16/wave: A 2 chunks, B 4 chunks
        const bf16_t* ap = aSrc + t*64;
        const bf16_t* bp = bSrc + t*64;
        gload16(ap,               &LS[bi][(0         + wave*8)*64]);
        gload16(ap + (size_t)64*K, &LS[bi][(64        + wave*8)*64]);
        gload16(bp,               &LS[bi][(128 +   0 + wave*8)*64]);
        gload16(bp + (size_t)64*K, &LS[bi][(128 +  64 + wave*8)*64]);
        gload16(bp + (size_t)128*K,&LS[bi][(128 + 128 + wave*8)*64]);
        gload16(bp + (size_t)192*K,&LS[bi][(128 + 192 + wave*8)*64]);
    };

    // prologue: tiles 0,1 -> bufs 0,1; wait tile 0 (leave tile 1's 6 in flight)
    stage(0, 0);
    stage(1, 1);
    asm volatile("s_waitcnt vmcnt(6)" ::: "memory");
    BARRIER;

    int bi = 0;
    for (int t = 0; t < NT; ++t) {
        bf16x8 af[4][2], bfr[4][2];
        #pragma unroll
        for (int mi = 0; mi < 4; mi++)
            #pragma unroll
            for (int kk = 0; kk < 2; kk++)
                af[mi][kk] = *(const bf16x8*)
                    &LS[bi][(wm + mi*16 + l16)*64 + ((kk*4+quad)^fsw)*8];
        #pragma unroll
        for (int ni = 0; ni < 4; ni++)
            #pragma unroll
            for (int kk = 0; kk < 2; kk++)
                bfr[ni][kk] = *(const bf16x8*)
                    &LS[bi][(128 + wn + ni*16 + l16)*64 + ((kk*4+quad)^fsw)*8];

        if (t + 2 < NT) {
            int b2 = bi + 2; if (b2 >= 3) b2 -= 3;
            stage(b2, t + 2);
        }
        BARRIER;
        asm volatile("s_waitcnt lgkmcnt(0)" ::: "memory");
        __builtin_amdgcn_sched_barrier(0);
        __builtin_amdgcn_s_setprio(1);
        #pragma unroll
        for (int mi = 0; mi < 4; mi++)
            #pragma unroll
            for (int ni = 0; ni < 4; ni++)
                #pragma unroll
                for (int kk = 0; kk < 2; kk++)
                    acc[mi][ni] = mfma16(af[mi][kk], bfr[ni][kk], acc[mi][ni]);
        __builtin_amdgcn_s_setprio(0);
        // drain the batch consumed next phase; keep newest batch in flight
        if (t + 2 < NT)      asm volatile("s_waitcnt vmcnt(6)" ::: "memory");
        else if (t + 1 < NT) asm volatile("s_waitcnt vmcnt(0)" ::: "memory");
        BARRIER;
        bi = bi + 1; if (bi >= 3) bi = 0;
    }

    // ---- epilogue: bias + store
    float bv[4];
    #pragma unroll
    for (int ni = 0; ni < 4; ni++) bv[ni] = biasp[n0 + wn + ni*16 + l16];

    #pragma unroll
    for (int mi = 0; mi < 4; mi++)
        #pragma unroll
        for (int ni = 0; ni < 4; ni++)
            #pragma unroll
            for (int r = 0; r < 4; r++) {
                int row = m0 + wm + mi*16 + quad*4 + r;
                int col = n0 + wn + ni*16 + l16;
                float v = acc[mi][ni][r] + bv[ni];
                if (OUT_IS_F32) ((float*)Cp)[(size_t)row * N + col] = v;
                else            ((bf16_t*)Cp)[(size_t)row * N + col] = (bf16_t)v;
            }
}

// ---------------------------------------------------------------------------
// Flash attention v11 — attn8 inner structure (single-buffered K/V, two
// barriers/tile: R6 showed dbuf+1-barrier ADDS DS contention, 78.6 vs 74.2),
// q-split to 128 rows/block (qi=2), grid 16x64=1024, __launch_bounds__(256,3).
// R2's q-split failure was the (256,4) bound squeezing VGPR to 64 -> spills;
// (256,3) caps at ~170, live state ~140 fits -> 3 blocks/CU, 3 waves/SIMD
// to cross-hide the serial QK^T -> exp2/pack -> PV chain. No setprio (also
// bundled in R2's failure; guide m190: setprio null/negative on lockstep).
// ---------------------------------------------------------------------------
__global__ __launch_bounds__(256, 3)
void attn11(const bf16_t* __restrict__ qkv, const bf16_t* __restrict__ vt,
            bf16_t* __restrict__ aout)
{
    __shared__ bf16_t Ks[64][72];      // [key][d]
    __shared__ bf16_t Vs[64][72];      // [d][key]
    __shared__ bf16_t Po[4][16][72];   // per-wave epilogue transpose tile

    const int tid  = threadIdx.x;
    const int wave = tid >> 6;
    const int lane = tid & 63;
    const int quad = lane >> 4;
    const int l16  = lane & 15;
    const int bh   = blockIdx.y;
    const int b    = bh >> 4;
    const int h    = bh & 15;
    const int qt   = blockIdx.x;       // 0..15 (128 q-rows each)
    const float kscale = 0.125f * 1.44269504088896340736f;

    // Q fragments (B-operand: n=q=l16, k=quad*8+j), pre-scaled by kscale
    bf16x8 qf[2][2];
    #pragma unroll
    for (int qi = 0; qi < 2; qi++) {
        const bf16_t* qrow = qkv + (size_t)(b*Sc + qt*128 + wave*32 + qi*16 + l16)*(3*Ec) + h*Dc;
        qf[qi][0] = *(const bf16x8*)(qrow + quad*8);
        qf[qi][1] = *(const bf16x8*)(qrow + 32 + quad*8);
        #pragma unroll
        for (int f = 0; f < 2; f++)
            #pragma unroll
            for (int e = 0; e < 8; e++)
                qf[qi][f][e] = (bf16_t)((float)qf[qi][f][e] * kscale);
    }

    f32x4 acc[4][2] = {};    // O^T accumulator [di][qi]: d=di*16+quad*4+r, q=qi*16+l16
    float lpart[2] = {};     // per-lane partial row sums (this quad's keys)

    const int krw   = tid >> 2;        // 0..63
    const int dbase = (tid & 3) * 16;  // 0/16/32/48

    const bf16_t* kbase = qkv + (size_t)(b*Sc + krw)*(3*Ec) + Ec + h*Dc + dbase;
    const bf16_t* vbase = vt + (size_t)bh*Dc*Sc + (size_t)krw*Sc + dbase;
    const size_t kstep = (size_t)64 * (3*Ec);
    uint4 ku0 = ((const uint4*)kbase)[0];
    uint4 ku1 = ((const uint4*)kbase)[1];
    uint4 vu0 = ((const uint4*)vbase)[0];
    uint4 vu1 = ((const uint4*)vbase)[1];

    for (int kt = 0; kt < Sc/64; kt++) {
        __syncthreads();
        *(uint4*)&Ks[krw][dbase]     = ku0;
        *(uint4*)&Ks[krw][dbase + 8] = ku1;
        *(uint4*)&Vs[krw][dbase]     = vu0;
        *(uint4*)&Vs[krw][dbase + 8] = vu1;
        __syncthreads();

        if (kt < Sc/64 - 1) {
            const bf16_t* kn = kbase + (size_t)(kt+1) * kstep;
            const bf16_t* vn = vbase + (kt+1) * 64;
            ku0 = ((const uint4*)kn)[0];
            ku1 = ((const uint4*)kn)[1];
            vu0 = ((const uint4*)vn)[0];
            vu1 = ((const uint4*)vn)[1];
        }

        // K fragments (A-operand: m=key=l16, k=quad*8+j)
        bf16x8 kf[4][2];
        #pragma unroll
        for (int ki = 0; ki < 4; ki++) {
            kf[ki][0] = *(const bf16x8*)&Ks[ki*16 + l16][quad*8];
            kf[ki][1] = *(const bf16x8*)&Ks[ki*16 + l16][32 + quad*8];
        }

        // S^T = K Q^T ; p = exp2(s) packed bf16, kept in registers
        bf16x4 pp[4][2];   // [ki][qi]: reg r = key ki*16+quad*4+r, col q=l16
        #pragma unroll
        for (int ki = 0; ki < 4; ki++) {
            #pragma unroll
            for (int qi = 0; qi < 2; qi++) {
                f32x4 z = {};
                z = mfma16(kf[ki][0], qf[qi][0], z);
                z = mfma16(kf[ki][1], qf[qi][1], z);
                float p0 = __ocml_native_exp2_f32(z[0]);
                float p1 = __ocml_native_exp2_f32(z[1]);
                float p2 = __ocml_native_exp2_f32(z[2]);
                float p3 = __ocml_native_exp2_f32(z[3]);
                lpart[qi] += (p0 + p1) + (p2 + p3);
                bf16x4 w;
                w[0] = (bf16_t)p0; w[1] = (bf16_t)p1;
                w[2] = (bf16_t)p2; w[3] = (bf16_t)p3;
                pp[ki][qi] = w;
            }
        }

        // O^T += V^T P^T : paired-K packing, keys c*32.. covered per c
        #pragma unroll
        for (int c = 0; c < 2; c++) {
            bf16x8 pcat[2];
            #pragma unroll
            for (int qi = 0; qi < 2; qi++)
                pcat[qi] = __builtin_shufflevector(pp[2*c][qi], pp[2*c+1][qi],
                                                   0,1,2,3,4,5,6,7);
            #pragma unroll
            for (int di = 0; di < 4; di++) {
                bf16x4 v0 = *(const bf16x4*)&Vs[di*16 + l16][c*32 + 4*quad];
                bf16x4 v1 = *(const bf16x4*)&Vs[di*16 + l16][c*32 + 16 + 4*quad];
                bf16x8 vf = __builtin_shufflevector(v0, v1, 0,1,2,3,4,5,6,7);
                #pragma unroll
                for (int qi = 0; qi < 2; qi++)
                    acc[di][qi] = mfma16(vf, pcat[qi], acc[di][qi]);
            }
        }
    }

    // ---- epilogue: reduce l across quads (keys), normalize, transpose via
    // per-wave LDS slice, coalesced stores ----
    float inv[2];
    #pragma unroll
    for (int qi = 0; qi < 2; qi++) {
        float l = lpart[qi];
        l += __shfl_xor(l, 16);
        l += __shfl_xor(l, 32);
        inv[qi] = 1.0f / l;
    }

    const int qrd  = lane >> 2;          // 0..15: token row within qi-slice
    const int dch  = (lane & 3) * 16;    // d chunk for read-back
    #pragma unroll
    for (int qi = 0; qi < 2; qi++) {
        // write O^T slice: Po[q=l16][d=di*16+quad*4 .. +3] (b64, 2-way free)
        #pragma unroll
        for (int di = 0; di < 4; di++) {
            alignas(8) bf16_t w[4];
            #pragma unroll
            for (int r = 0; r < 4; r++)
                w[r] = (bf16_t)(acc[di][qi][r] * inv[qi]);
            *(uint2*)&Po[wave][l16][di*16 + quad*4] = *(uint2*)w;
        }
        asm volatile("s_waitcnt lgkmcnt(0)" ::: "memory");
        // read back token-major, store coalesced (4 lanes = 128B per token)
        uint4 o0 = *(const uint4*)&Po[wave][qrd][dch];
        uint4 o1 = *(const uint4*)&Po[wave][qrd][dch + 8];
        bf16_t* dst = aout + (size_t)(b*Sc + qt*128 + wave*32 + qi*16 + qrd)*Ec + h*Dc + dch;
        ((uint4*)dst)[0] = o0;
        ((uint4*)dst)[1] = o1;
        // WAR safe across qi: DS pipe executes a wave's ops in order
    }
}

extern "C" void kernel_launch(void* const* d_in, const int* in_sizes, int n_in,
                              void* d_out, int out_size, void* d_ws, size_t ws_size,
                              hipStream_t stream) {
    const float* query = (const float*)d_in[0];
    const float* W_qkv = (const float*)d_in[3];
    const float* b_qkv = (const float*)d_in[4];
    const float* W_out = (const float*)d_in[5];
    const float* b_out = (const float*)d_in[6];
    float* out = (float*)d_out;

    const size_t MT = (size_t)Bc * Sc;             // 8192 tokens
    char* ws = (char*)d_ws;
    size_t off = 0;
    bf16_t* qbf    = (bf16_t*)(ws + off); off += MT*Ec*2;            // query bf16 / attn out
    bf16_t* qkv_ws = (bf16_t*)(ws + off); off += MT*3*Ec*2;
    bf16_t* vt_ws  = (bf16_t*)(ws + off); off += MT*Ec*2;
    bf16_t* wqkv_t = (bf16_t*)(ws + off); off += (size_t)3*Ec*Ec*2;
    bf16_t* wout_t = (bf16_t*)(ws + off); off += (size_t)Ec*Ec*2;

    cvt_bf16<<<(MT*Ec/4 + 255)/256, 256, 0, stream>>>(query, qbf, (int)(MT*Ec/4));
    transpose_w<<<dim3(3*Ec/64, Ec/64), 256, 0, stream>>>(W_qkv, wqkv_t, Ec, 3*Ec);
    transpose_w<<<dim3(Ec/64, Ec/64), 256, 0, stream>>>(W_out, wout_t, Ec, Ec);

    gemm3b<0><<<dim3(3*Ec/256, MT/128), 512, 0, stream>>>(
        qbf, wqkv_t, b_qkv, qkv_ws, (int)MT, 3*Ec, Ec);

    transpose_v<<<dim3(Sc/64, Bc*Hc), 256, 0, stream>>>(qkv_ws, vt_ws);

    attn11<<<dim3(Sc/128, Bc*Hc), 256, 0, stream>>>(qkv_ws, vt_ws, qbf);

    gemm3b<1><<<dim3(Ec/256, MT/128), 512, 0, stream>>>(
        qbf, wout_t, b_out, out, (int)MT, Ec, Ec);
}

// Round 13
// 303.892 us; speedup vs baseline: 1.0374x; 1.0374x over previous
//
#include <hip/hip_runtime.h>
#include <hip/hip_bf16.h>

#define Bc 4
#define Sc 2048
#define Ec 1024
#define Hc 16
#define Dc 64

typedef __bf16 bf16_t;
typedef __bf16 bf16x4 __attribute__((ext_vector_type(4)));
typedef __bf16 bf16x8 __attribute__((ext_vector_type(8)));
typedef float f32x4 __attribute__((ext_vector_type(4)));

extern "C" __device__ float __ocml_native_exp2_f32(float);  // bare v_exp_f32

__device__ __forceinline__ f32x4 mfma16(bf16x8 a, bf16x8 b, f32x4 c) {
    return __builtin_amdgcn_mfma_f32_16x16x32_bf16(a, b, c, 0, 0, 0);
}

// async global->LDS, 16B per lane; LDS dst = wave-uniform base + lane*16
__device__ __forceinline__ void gload16(const bf16_t* g, bf16_t* l) {
    __builtin_amdgcn_global_load_lds(
        (const __attribute__((address_space(1))) unsigned int*)g,
        (__attribute__((address_space(3))) unsigned int*)l, 16, 0, 0);
}

#define FENCE asm volatile("" ::: "memory")
#define BARRIER do { FENCE; __builtin_amdgcn_s_barrier(); FENCE; } while (0)

// ---------------------------------------------------------------------------
// f32 -> bf16 elementwise convert (vectorized)
// ---------------------------------------------------------------------------
__global__ __launch_bounds__(256)
void cvt_bf16(const float* __restrict__ in, bf16_t* __restrict__ out, int n4)
{
    int i = blockIdx.x * 256 + threadIdx.x;
    if (i >= n4) return;
    float4 v = ((const float4*)in)[i];
    alignas(8) bf16_t o[4];
    o[0] = (bf16_t)v.x; o[1] = (bf16_t)v.y; o[2] = (bf16_t)v.z; o[3] = (bf16_t)v.w;
    ((uint2*)out)[i] = *(uint2*)o;
}

// ---------------------------------------------------------------------------
// W[K][N] f32 -> Wt[N][K] bf16, 64x64 LDS tiles
// ---------------------------------------------------------------------------
__global__ __launch_bounds__(256)
void transpose_w(const float* __restrict__ W, bf16_t* __restrict__ Wt, int K, int N)
{
    __shared__ float T[64][65];
    const int kt = blockIdx.y, nt = blockIdx.x;
    const int r = threadIdx.x >> 4;          // 0..15
    const int c = (threadIdx.x & 15) * 4;    // 0..60
    #pragma unroll
    for (int p = 0; p < 4; p++) {
        float4 v = *(const float4*)(W + (size_t)(kt*64 + r + p*16)*N + nt*64 + c);
        T[r + p*16][c] = v.x; T[r + p*16][c+1] = v.y;
        T[r + p*16][c+2] = v.z; T[r + p*16][c+3] = v.w;
    }
    __syncthreads();
    #pragma unroll
    for (int p = 0; p < 4; p++) {
        int n = nt*64 + r + p*16;
        alignas(8) bf16_t tmp[4];
        #pragma unroll
        for (int j = 0; j < 4; j++) tmp[j] = (bf16_t)T[c + j][r + p*16];
        *(uint2*)(Wt + (size_t)n*K + kt*64 + c) = *(uint2*)tmp;
    }
}

// ---------------------------------------------------------------------------
// V slice of qkv [token][3E] -> Vt[bh][d][s], natural key order.
// ---------------------------------------------------------------------------
__global__ __launch_bounds__(256)
void transpose_v(const bf16_t* __restrict__ qkv, bf16_t* __restrict__ vt)
{
    __shared__ bf16_t T[64][72];
    const int bh = blockIdx.y, st = blockIdx.x;
    const int b = bh >> 4, h = bh & 15;
    const int sr = threadIdx.x >> 3;         // 0..31
    const int dc = (threadIdx.x & 7) * 8;    // 0..56
    #pragma unroll
    for (int p = 0; p < 2; p++) {
        const bf16_t* src = qkv + (size_t)(b*Sc + st*64 + sr + p*32)*(3*Ec) + 2*Ec + h*Dc + dc;
        *(uint4*)&T[sr + p*32][dc] = *(const uint4*)src;
    }
    __syncthreads();
    const int dr = threadIdx.x >> 3;
    const int sc2 = (threadIdx.x & 7) * 8;
    #pragma unroll
    for (int p = 0; p < 2; p++) {
        alignas(16) bf16_t tmp[8];
        #pragma unroll
        for (int j = 0; j < 8; j++)
            tmp[j] = T[sc2 + j][dr + p*32];
        *(uint4*)(vt + (size_t)bh*Dc*Sc + (size_t)(dr + p*32)*Sc + st*64 + sc2) = *(uint4*)tmp;
    }
}

// ---------------------------------------------------------------------------
// gemm3b: C[M,N] = A[M,K]@Bt[N,K]^T + bias.
// Triple-buffered counted-vmcnt schedule: BM=128 BN=256 BK=64, 8 waves,
// per-wave 64x64 out (32 MFMA/phase), LDS 144KB, vmcnt(6) per phase,
// chunk-XOR swizzle, XCD-aware block swizzle. (R5: both GEMMs < 74us.)
// ---------------------------------------------------------------------------
template<int OUT_IS_F32>
__global__ __launch_bounds__(512)
void gemm3b(const bf16_t* __restrict__ A, const bf16_t* __restrict__ Bt,
            const float* __restrict__ biasp, void* __restrict__ Cp,
            int M, int N, int K)
{
    // per buffer: A rows [0,128), B rows [128,384), 64 elems/row
    __shared__ bf16_t LS[3][384*64];

    const int tid  = threadIdx.x;
    const int wave = tid >> 6;          // 0..7
    const int lane = tid & 63;
    const int quad = lane >> 4;
    const int l16  = lane & 15;
    const int wm   = (wave >> 2) * 64;  // 2 M-groups x 64 rows
    const int wn   = (wave & 3) * 64;   // 4 N-groups x 64 cols

    // XCD-aware swizzle (both grids are multiples of 8)
    const int nwg = gridDim.x * gridDim.y;
    const int bid = blockIdx.y * gridDim.x + blockIdx.x;
    const int cpx = nwg >> 3;
    const int swz = (bid & 7) * cpx + (bid >> 3);
    const int nbx = N >> 8;
    const int m0  = (swz / nbx) * 128;
    const int n0  = (swz % nbx) * 256;

    const int NT = K >> 6;

    // staging: each wave stages 8 rows/chunk; src col pre-swizzled so linear
    // LDS dest ends up chunk-XOR-permuted: phys_chunk = log_chunk ^ ((row>>1)&7)
    const int srow = lane >> 3;                                  // 0..7
    const int sch  = (lane & 7) ^ ((wave*4 + (lane >> 4)) & 7);  // logical 16B chunk
    const bf16_t* aSrc = A  + (size_t)(m0 + wave*8 + srow)*K + sch*8;
    const bf16_t* bSrc = Bt + (size_t)(n0 + wave*8 + srow)*K + sch*8;

    const int fsw = (l16 >> 1) & 7;   // read-side swizzle (same involution)

    f32x4 acc[4][4] = {};

    auto stage = [&](int bi, int t) {   // 6 gload16/wave: A 2 chunks, B 4 chunks
        const bf16_t* ap = aSrc + t*64;
        const bf16_t* bp = bSrc + t*64;
        gload16(ap,               &LS[bi][(0         + wave*8)*64]);
        gload16(ap + (size_t)64*K, &LS[bi][(64        + wave*8)*64]);
        gload16(bp,               &LS[bi][(128 +   0 + wave*8)*64]);
        gload16(bp + (size_t)64*K, &LS[bi][(128 +  64 + wave*8)*64]);
        gload16(bp + (size_t)128*K,&LS[bi][(128 + 128 + wave*8)*64]);
        gload16(bp + (size_t)192*K,&LS[bi][(128 + 192 + wave*8)*64]);
    };

    // prologue: tiles 0,1 -> bufs 0,1; wait tile 0 (leave tile 1's 6 in flight)
    stage(0, 0);
    stage(1, 1);
    asm volatile("s_waitcnt vmcnt(6)" ::: "memory");
    BARRIER;

    int bi = 0;
    for (int t = 0; t < NT; ++t) {
        bf16x8 af[4][2], bfr[4][2];
        #pragma unroll
        for (int mi = 0; mi < 4; mi++)
            #pragma unroll
            for (int kk = 0; kk < 2; kk++)
                af[mi][kk] = *(const bf16x8*)
                    &LS[bi][(wm + mi*16 + l16)*64 + ((kk*4+quad)^fsw)*8];
        #pragma unroll
        for (int ni = 0; ni < 4; ni++)
            #pragma unroll
            for (int kk = 0; kk < 2; kk++)
                bfr[ni][kk] = *(const bf16x8*)
                    &LS[bi][(128 + wn + ni*16 + l16)*64 + ((kk*4+quad)^fsw)*8];

        if (t + 2 < NT) {
            int b2 = bi + 2; if (b2 >= 3) b2 -= 3;
            stage(b2, t + 2);
        }
        BARRIER;
        asm volatile("s_waitcnt lgkmcnt(0)" ::: "memory");
        __builtin_amdgcn_sched_barrier(0);
        __builtin_amdgcn_s_setprio(1);
        #pragma unroll
        for (int mi = 0; mi < 4; mi++)
            #pragma unroll
            for (int ni = 0; ni < 4; ni++)
                #pragma unroll
                for (int kk = 0; kk < 2; kk++)
                    acc[mi][ni] = mfma16(af[mi][kk], bfr[ni][kk], acc[mi][ni]);
        __builtin_amdgcn_s_setprio(0);
        // drain the batch consumed next phase; keep newest batch in flight
        if (t + 2 < NT)      asm volatile("s_waitcnt vmcnt(6)" ::: "memory");
        else if (t + 1 < NT) asm volatile("s_waitcnt vmcnt(0)" ::: "memory");
        BARRIER;
        bi = bi + 1; if (bi >= 3) bi = 0;
    }

    // ---- epilogue: bias + store
    float bv[4];
    #pragma unroll
    for (int ni = 0; ni < 4; ni++) bv[ni] = biasp[n0 + wn + ni*16 + l16];

    #pragma unroll
    for (int mi = 0; mi < 4; mi++)
        #pragma unroll
        for (int ni = 0; ni < 4; ni++)
            #pragma unroll
            for (int r = 0; r < 4; r++) {
                int row = m0 + wm + mi*16 + quad*4 + r;
                int col = n0 + wn + ni*16 + l16;
                float v = acc[mi][ni][r] + bv[ni];
                if (OUT_IS_F32) ((float*)Cp)[(size_t)row * N + col] = v;
                else            ((bf16_t*)Cp)[(size_t)row * N + col] = (bf16_t)v;
            }
}

// ---------------------------------------------------------------------------
// Flash attention v12 = attn8 (74.2us known-good inner loop, 2 barriers/tile,
// 128 VGPR, 2 blocks/CU) + XCD-locality grid swap.
// R12 lesson: q-split regresses either way (R2: spills; R12: VGPR=60 remat,
// 2x DS traffic, 89.4us). Occupancy path CLOSED.
// This change: grid (bh, qt) instead of (qt, bh). Dispatch id = y*64+x ->
// XCD = id%8 = bh%8, so all 8 q-blocks sharing a bh's K/V land on ONE XCD
// (same L2) instead of 8 different ones. K/V per XCD: 8 bh x 512KB = 4MB =
// L2 size -> K/V fetched from HBM once per XCD, not 8x.
// Predict: FETCH 139 -> ~55-75MB, dur 74.2 -> 66-71us.
// ---------------------------------------------------------------------------
__global__ __launch_bounds__(256, 2)
void attn12(const bf16_t* __restrict__ qkv, const bf16_t* __restrict__ vt,
            bf16_t* __restrict__ aout)
{
    __shared__ bf16_t Ks[64][72];      // [key][d]
    __shared__ bf16_t Vs[64][72];      // [d][key]
    __shared__ bf16_t Po[4][16][72];   // per-wave epilogue transpose tile

    const int tid  = threadIdx.x;
    const int wave = tid >> 6;
    const int lane = tid & 63;
    const int quad = lane >> 4;
    const int l16  = lane & 15;
    const int bh   = blockIdx.x;       // <- swapped: XCD = bh%8
    const int b    = bh >> 4;
    const int h    = bh & 15;
    const int qt   = blockIdx.y;       // 0..7 (256 q-rows each)
    const float kscale = 0.125f * 1.44269504088896340736f;

    // Q fragments (B-operand: n=q=l16, k=quad*8+j), pre-scaled by kscale
    bf16x8 qf[4][2];
    #pragma unroll
    for (int qi = 0; qi < 4; qi++) {
        const bf16_t* qrow = qkv + (size_t)(b*Sc + qt*256 + wave*64 + qi*16 + l16)*(3*Ec) + h*Dc;
        qf[qi][0] = *(const bf16x8*)(qrow + quad*8);
        qf[qi][1] = *(const bf16x8*)(qrow + 32 + quad*8);
        #pragma unroll
        for (int f = 0; f < 2; f++)
            #pragma unroll
            for (int e = 0; e < 8; e++)
                qf[qi][f][e] = (bf16_t)((float)qf[qi][f][e] * kscale);
    }

    f32x4 acc[4][4] = {};    // O^T accumulator [di][qi]: d=di*16+quad*4+r, q=qi*16+l16
    float lpart[4] = {};     // per-lane partial row sums (this quad's keys)

    const int krw   = tid >> 2;        // 0..63
    const int dbase = (tid & 3) * 16;  // 0/16/32/48

    const bf16_t* kbase = qkv + (size_t)(b*Sc + krw)*(3*Ec) + Ec + h*Dc + dbase;
    const bf16_t* vbase = vt + (size_t)bh*Dc*Sc + (size_t)krw*Sc + dbase;
    const size_t kstep = (size_t)64 * (3*Ec);
    uint4 ku0 = ((const uint4*)kbase)[0];
    uint4 ku1 = ((const uint4*)kbase)[1];
    uint4 vu0 = ((const uint4*)vbase)[0];
    uint4 vu1 = ((const uint4*)vbase)[1];

    for (int kt = 0; kt < Sc/64; kt++) {
        __syncthreads();
        *(uint4*)&Ks[krw][dbase]     = ku0;
        *(uint4*)&Ks[krw][dbase + 8] = ku1;
        *(uint4*)&Vs[krw][dbase]     = vu0;
        *(uint4*)&Vs[krw][dbase + 8] = vu1;
        __syncthreads();

        if (kt < Sc/64 - 1) {
            const bf16_t* kn = kbase + (size_t)(kt+1) * kstep;
            const bf16_t* vn = vbase + (kt+1) * 64;
            ku0 = ((const uint4*)kn)[0];
            ku1 = ((const uint4*)kn)[1];
            vu0 = ((const uint4*)vn)[0];
            vu1 = ((const uint4*)vn)[1];
        }

        // K fragments (A-operand: m=key=l16, k=quad*8+j)
        bf16x8 kf[4][2];
        #pragma unroll
        for (int ki = 0; ki < 4; ki++) {
            kf[ki][0] = *(const bf16x8*)&Ks[ki*16 + l16][quad*8];
            kf[ki][1] = *(const bf16x8*)&Ks[ki*16 + l16][32 + quad*8];
        }

        // S^T = K Q^T ; p = exp2(s) packed bf16, kept in registers
        bf16x4 pp[4][4];   // [ki][qi]: reg r = key ki*16+quad*4+r, col q=l16
        #pragma unroll
        for (int ki = 0; ki < 4; ki++) {
            #pragma unroll
            for (int qi = 0; qi < 4; qi++) {
                f32x4 z = {};
                z = mfma16(kf[ki][0], qf[qi][0], z);
                z = mfma16(kf[ki][1], qf[qi][1], z);
                float p0 = __ocml_native_exp2_f32(z[0]);
                float p1 = __ocml_native_exp2_f32(z[1]);
                float p2 = __ocml_native_exp2_f32(z[2]);
                float p3 = __ocml_native_exp2_f32(z[3]);
                lpart[qi] += (p0 + p1) + (p2 + p3);
                bf16x4 w;
                w[0] = (bf16_t)p0; w[1] = (bf16_t)p1;
                w[2] = (bf16_t)p2; w[3] = (bf16_t)p3;
                pp[ki][qi] = w;
            }
        }

        // O^T += V^T P^T : paired-K packing, keys c*32.. covered per c
        #pragma unroll
        for (int c = 0; c < 2; c++) {
            bf16x8 pcat[4];
            #pragma unroll
            for (int qi = 0; qi < 4; qi++)
                pcat[qi] = __builtin_shufflevector(pp[2*c][qi], pp[2*c+1][qi],
                                                   0,1,2,3,4,5,6,7);
            #pragma unroll
            for (int di = 0; di < 4; di++) {
                bf16x4 v0 = *(const bf16x4*)&Vs[di*16 + l16][c*32 + 4*quad];
                bf16x4 v1 = *(const bf16x4*)&Vs[di*16 + l16][c*32 + 16 + 4*quad];
                bf16x8 vf = __builtin_shufflevector(v0, v1, 0,1,2,3,4,5,6,7);
                #pragma unroll
                for (int qi = 0; qi < 4; qi++)
                    acc[di][qi] = mfma16(vf, pcat[qi], acc[di][qi]);
            }
        }
    }

    // ---- epilogue: reduce l across quads (keys), normalize, transpose via
    // per-wave LDS slice, coalesced stores ----
    float inv[4];
    #pragma unroll
    for (int qi = 0; qi < 4; qi++) {
        float l = lpart[qi];
        l += __shfl_xor(l, 16);
        l += __shfl_xor(l, 32);
        inv[qi] = 1.0f / l;
    }

    const int qrd  = lane >> 2;          // 0..15: token row within qi-slice
    const int dch  = (lane & 3) * 16;    // d chunk for read-back
    #pragma unroll
    for (int qi = 0; qi < 4; qi++) {
        // write O^T slice: Po[q=l16][d=di*16+quad*4 .. +3] (b64, 2-way free)
        #pragma unroll
        for (int di = 0; di < 4; di++) {
            alignas(8) bf16_t w[4];
            #pragma unroll
            for (int r = 0; r < 4; r++)
                w[r] = (bf16_t)(acc[di][qi][r] * inv[qi]);
            *(uint2*)&Po[wave][l16][di*16 + quad*4] = *(uint2*)w;
        }
        asm volatile("s_waitcnt lgkmcnt(0)" ::: "memory");
        // read back token-major, store coalesced (4 lanes = 128B per token)
        uint4 o0 = *(const uint4*)&Po[wave][qrd][dch];
        uint4 o1 = *(const uint4*)&Po[wave][qrd][dch + 8];
        bf16_t* dst = aout + (size_t)(b*Sc + qt*256 + wave*64 + qi*16 + qrd)*Ec + h*Dc + dch;
        ((uint4*)dst)[0] = o0;
        ((uint4*)dst)[1] = o1;
        // WAR safe across qi: DS pipe executes a wave's ops in order
    }
}

extern "C" void kernel_launch(void* const* d_in, const int* in_sizes, int n_in,
                              void* d_out, int out_size, void* d_ws, size_t ws_size,
                              hipStream_t stream) {
    const float* query = (const float*)d_in[0];
    const float* W_qkv = (const float*)d_in[3];
    const float* b_qkv = (const float*)d_in[4];
    const float* W_out = (const float*)d_in[5];
    const float* b_out = (const float*)d_in[6];
    float* out = (float*)d_out;

    const size_t MT = (size_t)Bc * Sc;             // 8192 tokens
    char* ws = (char*)d_ws;
    size_t off = 0;
    bf16_t* qbf    = (bf16_t*)(ws + off); off += MT*Ec*2;            // query bf16 / attn out
    bf16_t* qkv_ws = (bf16_t*)(ws + off); off += MT*3*Ec*2;
    bf16_t* vt_ws  = (bf16_t*)(ws + off); off += MT*Ec*2;
    bf16_t* wqkv_t = (bf16_t*)(ws + off); off += (size_t)3*Ec*Ec*2;
    bf16_t* wout_t = (bf16_t*)(ws + off); off += (size_t)Ec*Ec*2;

    cvt_bf16<<<(MT*Ec/4 + 255)/256, 256, 0, stream>>>(query, qbf, (int)(MT*Ec/4));
    transpose_w<<<dim3(3*Ec/64, Ec/64), 256, 0, stream>>>(W_qkv, wqkv_t, Ec, 3*Ec);
    transpose_w<<<dim3(Ec/64, Ec/64), 256, 0, stream>>>(W_out, wout_t, Ec, Ec);

    gemm3b<0><<<dim3(3*Ec/256, MT/128), 512, 0, stream>>>(
        qbf, wqkv_t, b_qkv, qkv_ws, (int)MT, 3*Ec, Ec);

    transpose_v<<<dim3(Sc/64, Bc*Hc), 256, 0, stream>>>(qkv_ws, vt_ws);

    attn12<<<dim3(Bc*Hc, Sc/256), 256, 0, stream>>>(qkv_ws, vt_ws, qbf);

    gemm3b<1><<<dim3(Ec/256, MT/128), 512, 0, stream>>>(
        qbf, wout_t, b_out, out, (int)MT, Ec, Ec);
}

// Round 17
// 297.758 us; speedup vs baseline: 1.0588x; 1.0206x over previous
//
#include <hip/hip_runtime.h>
#include <hip/hip_bf16.h>

#define Bc 4
#define Sc 2048
#define Ec 1024
#define Hc 16
#define Dc 64

typedef __bf16 bf16_t;
typedef __bf16 bf16x4 __attribute__((ext_vector_type(4)));
typedef __bf16 bf16x8 __attribute__((ext_vector_type(8)));
typedef float f32x4 __attribute__((ext_vector_type(4)));

extern "C" __device__ float __ocml_native_exp2_f32(float);  // bare v_exp_f32

__device__ __forceinline__ f32x4 mfma16(bf16x8 a, bf16x8 b, f32x4 c) {
    return __builtin_amdgcn_mfma_f32_16x16x32_bf16(a, b, c, 0, 0, 0);
}

// async global->LDS, 16B per lane; LDS dst = wave-uniform base + lane*16
__device__ __forceinline__ void gload16(const bf16_t* g, bf16_t* l) {
    __builtin_amdgcn_global_load_lds(
        (const __attribute__((address_space(1))) unsigned int*)g,
        (__attribute__((address_space(3))) unsigned int*)l, 16, 0, 0);
}

#define FENCE asm volatile("" ::: "memory")
#define BARRIER do { FENCE; __builtin_amdgcn_s_barrier(); FENCE; } while (0)

// ---------------------------------------------------------------------------
// prep: fused {f32->bf16 convert of query} + {W_qkv transpose} + {W_out
// transpose}. R13 budget analysis: ~90us of the 303.9 total is launch/gap
// overhead across 7 dispatches (~10us each per rocprof.md); merging the 3
// independent preprocessing kernels into one saves 2 launches.
// Block ranges: [0,8192) cvt; [8192,8960) W_qkv 48x16; [8960,9216) W_out 16x16.
// ---------------------------------------------------------------------------
__global__ __launch_bounds__(256)
void prep(const float* __restrict__ query, bf16_t* __restrict__ qbf,
          const float* __restrict__ W_qkv, bf16_t* __restrict__ wqkv_t,
          const float* __restrict__ W_out, bf16_t* __restrict__ wout_t,
          int n4)
{
    __shared__ float T[64][65];
    const int blk = blockIdx.x;
    if (blk < 8192) {                       // ---- cvt_bf16 body
        int i = blk * 256 + threadIdx.x;
        if (i < n4) {
            float4 v = ((const float4*)query)[i];
            alignas(8) bf16_t o[4];
            o[0] = (bf16_t)v.x; o[1] = (bf16_t)v.y;
            o[2] = (bf16_t)v.z; o[3] = (bf16_t)v.w;
            ((uint2*)qbf)[i] = *(uint2*)o;
        }
        return;
    }
    // ---- transpose_w body (runtime K,N)
    const float* W; bf16_t* Wt; int K, N, kt, nt;
    if (blk < 8192 + 768) { int id = blk - 8192; W = W_qkv; Wt = wqkv_t; K = Ec; N = 3*Ec; nt = id % 48; kt = id / 48; }
    else                  { int id = blk - 8960; W = W_out; Wt = wout_t; K = Ec; N = Ec;   nt = id % 16; kt = id / 16; }
    const int r = threadIdx.x >> 4;          // 0..15
    const int c = (threadIdx.x & 15) * 4;    // 0..60
    #pragma unroll
    for (int p = 0; p < 4; p++) {
        float4 v = *(const float4*)(W + (size_t)(kt*64 + r + p*16)*N + nt*64 + c);
        T[r + p*16][c] = v.x; T[r + p*16][c+1] = v.y;
        T[r + p*16][c+2] = v.z; T[r + p*16][c+3] = v.w;
    }
    __syncthreads();
    #pragma unroll
    for (int p = 0; p < 4; p++) {
        int n = nt*64 + r + p*16;
        alignas(8) bf16_t tmp[4];
        #pragma unroll
        for (int j = 0; j < 4; j++) tmp[j] = (bf16_t)T[c + j][r + p*16];
        *(uint2*)(Wt + (size_t)n*K + kt*64 + c) = *(uint2*)tmp;
    }
}

// ---------------------------------------------------------------------------
// gemm3b: C[M,N] = A[M,K]@Bt[N,K]^T + bias.
// Triple-buffered counted-vmcnt schedule: BM=128 BN=256 BK=64, 8 waves,
// per-wave 64x64 out (32 MFMA/phase), LDS 144KB, vmcnt(6) per phase,
// chunk-XOR swizzle, XCD-aware block swizzle. (R5: both GEMMs < 74us.)
// NEW (R13): when vtp != nullptr and this block's n0 is in the V region
// (n0 >= 2E), the epilogue writes vt[bh][d][s] directly (via an LS-restage
// transpose, LS is idle after the main loop) instead of C — this fuses the
// old transpose_v kernel away (its ~17us + ~10us launch). Values are
// bit-identical: same acc+bias -> bf16 path the old qkv_ws->tv route took.
// ---------------------------------------------------------------------------
template<int OUT_IS_F32>
__global__ __launch_bounds__(512)
void gemm3b(const bf16_t* __restrict__ A, const bf16_t* __restrict__ Bt,
            const float* __restrict__ biasp, void* __restrict__ Cp,
            int M, int N, int K, bf16_t* __restrict__ vtp)
{
    // per buffer: A rows [0,128), B rows [128,384), 64 elems/row
    __shared__ bf16_t LS[3][384*64];

    const int tid  = threadIdx.x;
    const int wave = tid >> 6;          // 0..7
    const int lane = tid & 63;
    const int quad = lane >> 4;
    const int l16  = lane & 15;
    const int wm   = (wave >> 2) * 64;  // 2 M-groups x 64 rows
    const int wn   = (wave & 3) * 64;   // 4 N-groups x 64 cols

    // XCD-aware swizzle (both grids are multiples of 8)
    const int nwg = gridDim.x * gridDim.y;
    const int bid = blockIdx.y * gridDim.x + blockIdx.x;
    const int cpx = nwg >> 3;
    const int swz = (bid & 7) * cpx + (bid >> 3);
    const int nbx = N >> 8;
    const int m0  = (swz / nbx) * 128;
    const int n0  = (swz % nbx) * 256;

    const int NT = K >> 6;

    // staging: each wave stages 8 rows/chunk; src col pre-swizzled so linear
    // LDS dest ends up chunk-XOR-permuted: phys_chunk = log_chunk ^ ((row>>1)&7)
    const int srow = lane >> 3;                                  // 0..7
    const int sch  = (lane & 7) ^ ((wave*4 + (lane >> 4)) & 7);  // logical 16B chunk
    const bf16_t* aSrc = A  + (size_t)(m0 + wave*8 + srow)*K + sch*8;
    const bf16_t* bSrc = Bt + (size_t)(n0 + wave*8 + srow)*K + sch*8;

    const int fsw = (l16 >> 1) & 7;   // read-side swizzle (same involution)

    f32x4 acc[4][4] = {};

    auto stage = [&](int bi, int t) {   // 6 gload16/wave: A 2 chunks, B 4 chunks
        const bf16_t* ap = aSrc + t*64;
        const bf16_t* bp = bSrc + t*64;
        gload16(ap,               &LS[bi][(0         + wave*8)*64]);
        gload16(ap + (size_t)64*K, &LS[bi][(64        + wave*8)*64]);
        gload16(bp,               &LS[bi][(128 +   0 + wave*8)*64]);
        gload16(bp + (size_t)64*K, &LS[bi][(128 +  64 + wave*8)*64]);
        gload16(bp + (size_t)128*K,&LS[bi][(128 + 128 + wave*8)*64]);
        gload16(bp + (size_t)192*K,&LS[bi][(128 + 192 + wave*8)*64]);
    };

    // prologue: tiles 0,1 -> bufs 0,1; wait tile 0 (leave tile 1's 6 in flight)
    stage(0, 0);
    stage(1, 1);
    asm volatile("s_waitcnt vmcnt(6)" ::: "memory");
    BARRIER;

    int bi = 0;
    for (int t = 0; t < NT; ++t) {
        bf16x8 af[4][2], bfr[4][2];
        #pragma unroll
        for (int mi = 0; mi < 4; mi++)
            #pragma unroll
            for (int kk = 0; kk < 2; kk++)
                af[mi][kk] = *(const bf16x8*)
                    &LS[bi][(wm + mi*16 + l16)*64 + ((kk*4+quad)^fsw)*8];
        #pragma unroll
        for (int ni = 0; ni < 4; ni++)
            #pragma unroll
            for (int kk = 0; kk < 2; kk++)
                bfr[ni][kk] = *(const bf16x8*)
                    &LS[bi][(128 + wn + ni*16 + l16)*64 + ((kk*4+quad)^fsw)*8];

        if (t + 2 < NT) {
            int b2 = bi + 2; if (b2 >= 3) b2 -= 3;
            stage(b2, t + 2);
        }
        BARRIER;
        asm volatile("s_waitcnt lgkmcnt(0)" ::: "memory");
        __builtin_amdgcn_sched_barrier(0);
        __builtin_amdgcn_s_setprio(1);
        #pragma unroll
        for (int mi = 0; mi < 4; mi++)
            #pragma unroll
            for (int ni = 0; ni < 4; ni++)
                #pragma unroll
                for (int kk = 0; kk < 2; kk++)
                    acc[mi][ni] = mfma16(af[mi][kk], bfr[ni][kk], acc[mi][ni]);
        __builtin_amdgcn_s_setprio(0);
        // drain the batch consumed next phase; keep newest batch in flight
        if (t + 2 < NT)      asm volatile("s_waitcnt vmcnt(6)" ::: "memory");
        else if (t + 1 < NT) asm volatile("s_waitcnt vmcnt(0)" ::: "memory");
        BARRIER;
        bi = bi + 1; if (bi >= 3) bi = 0;
    }

    // ---- epilogue: bias + store
    float bv[4];
    #pragma unroll
    for (int ni = 0; ni < 4; ni++) bv[ni] = biasp[n0 + wn + ni*16 + l16];

    if (!OUT_IS_F32 && vtp && n0 >= 2*Ec) {
        // ---- fused transpose_v: stage tile in LS as [col][s] (stride 136,
        // 16B-aligned rows, ~2-4 way banks), then coalesced vt writes.
        bf16_t* T = &LS[0][0];
        #pragma unroll
        for (int mi = 0; mi < 4; mi++)
            #pragma unroll
            for (int ni = 0; ni < 4; ni++) {
                const int cl = wn + ni*16 + l16;        // 0..255
                const int sb = wm + mi*16 + quad*4;     // 0..124, mult of 4
                alignas(8) bf16_t w[4];
                #pragma unroll
                for (int r = 0; r < 4; r++)
                    w[r] = (bf16_t)(acc[mi][ni][r] + bv[ni]);
                *(uint2*)&T[cl*136 + sb] = *(uint2*)w;
            }
        __syncthreads();
        const int b   = m0 >> 11;          // m0 / Sc
        const int sr0 = m0 & (Sc - 1);
        const int h0  = (n0 - 2*Ec) >> 6;
        const int s0  = (tid & 7) * 16;    // 8 threads cover s 0..127 per col
        #pragma unroll
        for (int cb = 0; cb < 4; cb++) {
            const int cl = cb*64 + (tid >> 3);          // 0..255
            const int bh = b*Hc + h0 + (cl >> 6);
            const int d  = cl & 63;
            bf16_t* dst = vtp + ((size_t)bh*Dc + d)*Sc + sr0 + s0;
            uint4 v0 = *(const uint4*)&T[cl*136 + s0];
            uint4 v1 = *(const uint4*)&T[cl*136 + s0 + 8];
            ((uint4*)dst)[0] = v0;
            ((uint4*)dst)[1] = v1;
        }
        return;
    }

    #pragma unroll
    for (int mi = 0; mi < 4; mi++)
        #pragma unroll
        for (int ni = 0; ni < 4; ni++)
            #pragma unroll
            for (int r = 0; r < 4; r++) {
                int row = m0 + wm + mi*16 + quad*4 + r;
                int col = n0 + wn + ni*16 + l16;
                float v = acc[mi][ni][r] + bv[ni];
                if (OUT_IS_F32) ((float*)Cp)[(size_t)row * N + col] = v;
                else            ((bf16_t*)Cp)[(size_t)row * N + col] = (bf16_t)v;
            }
}

// ---------------------------------------------------------------------------
// Flash attention v12 = attn8 known-good inner loop (2 barriers/tile, 128
// VGPR, 2 blocks/CU) + XCD-locality grid swap (R13: FETCH 139->27.7MB
// confirmed; dur flat -> attn is VALU/chain-bound, not latency-bound).
// Occupancy path closed (R2/R12); micro VALU fixes predict <=3us -> frozen.
// ---------------------------------------------------------------------------
__global__ __launch_bounds__(256, 2)
void attn12(const bf16_t* __restrict__ qkv, const bf16_t* __restrict__ vt,
            bf16_t* __restrict__ aout)
{
    __shared__ bf16_t Ks[64][72];      // [key][d]
    __shared__ bf16_t Vs[64][72];      // [d][key]
    __shared__ bf16_t Po[4][16][72];   // per-wave epilogue transpose tile

    const int tid  = threadIdx.x;
    const int wave = tid >> 6;
    const int lane = tid & 63;
    const int quad = lane >> 4;
    const int l16  = lane & 15;
    const int bh   = blockIdx.x;       // XCD = bh%8: all q-blocks of a bh share an XCD/L2
    const int b    = bh >> 4;
    const int h    = bh & 15;
    const int qt   = blockIdx.y;       // 0..7 (256 q-rows each)
    const float kscale = 0.125f * 1.44269504088896340736f;

    // Q fragments (B-operand: n=q=l16, k=quad*8+j), pre-scaled by kscale
    bf16x8 qf[4][2];
    #pragma unroll
    for (int qi = 0; qi < 4; qi++) {
        const bf16_t* qrow = qkv + (size_t)(b*Sc + qt*256 + wave*64 + qi*16 + l16)*(3*Ec) + h*Dc;
        qf[qi][0] = *(const bf16x8*)(qrow + quad*8);
        qf[qi][1] = *(const bf16x8*)(qrow + 32 + quad*8);
        #pragma unroll
        for (int f = 0; f < 2; f++)
            #pragma unroll
            for (int e = 0; e < 8; e++)
                qf[qi][f][e] = (bf16_t)((float)qf[qi][f][e] * kscale);
    }

    f32x4 acc[4][4] = {};    // O^T accumulator [di][qi]: d=di*16+quad*4+r, q=qi*16+l16
    float lpart[4] = {};     // per-lane partial row sums (this quad's keys)

    const int krw   = tid >> 2;        // 0..63
    const int dbase = (tid & 3) * 16;  // 0/16/32/48

    const bf16_t* kbase = qkv + (size_t)(b*Sc + krw)*(3*Ec) + Ec + h*Dc + dbase;
    const bf16_t* vbase = vt + (size_t)bh*Dc*Sc + (size_t)krw*Sc + dbase;
    const size_t kstep = (size_t)64 * (3*Ec);
    uint4 ku0 = ((const uint4*)kbase)[0];
    uint4 ku1 = ((const uint4*)kbase)[1];
    uint4 vu0 = ((const uint4*)vbase)[0];
    uint4 vu1 = ((const uint4*)vbase)[1];

    for (int kt = 0; kt < Sc/64; kt++) {
        __syncthreads();
        *(uint4*)&Ks[krw][dbase]     = ku0;
        *(uint4*)&Ks[krw][dbase + 8] = ku1;
        *(uint4*)&Vs[krw][dbase]     = vu0;
        *(uint4*)&Vs[krw][dbase + 8] = vu1;
        __syncthreads();

        if (kt < Sc/64 - 1) {
            const bf16_t* kn = kbase + (size_t)(kt+1) * kstep;
            const bf16_t* vn = vbase + (kt+1) * 64;
            ku0 = ((const uint4*)kn)[0];
            ku1 = ((const uint4*)kn)[1];
            vu0 = ((const uint4*)vn)[0];
            vu1 = ((const uint4*)vn)[1];
        }

        // K fragments (A-operand: m=key=l16, k=quad*8+j)
        bf16x8 kf[4][2];
        #pragma unroll
        for (int ki = 0; ki < 4; ki++) {
            kf[ki][0] = *(const bf16x8*)&Ks[ki*16 + l16][quad*8];
            kf[ki][1] = *(const bf16x8*)&Ks[ki*16 + l16][32 + quad*8];
        }

        // S^T = K Q^T ; p = exp2(s) packed bf16, kept in registers
        bf16x4 pp[4][4];   // [ki][qi]: reg r = key ki*16+quad*4+r, col q=l16
        #pragma unroll
        for (int ki = 0; ki < 4; ki++) {
            #pragma unroll
            for (int qi = 0; qi < 4; qi++) {
                f32x4 z = {};
                z = mfma16(kf[ki][0], qf[qi][0], z);
                z = mfma16(kf[ki][1], qf[qi][1], z);
                float p0 = __ocml_native_exp2_f32(z[0]);
                float p1 = __ocml_native_exp2_f32(z[1]);
                float p2 = __ocml_native_exp2_f32(z[2]);
                float p3 = __ocml_native_exp2_f32(z[3]);
                lpart[qi] += (p0 + p1) + (p2 + p3);
                bf16x4 w;
                w[0] = (bf16_t)p0; w[1] = (bf16_t)p1;
                w[2] = (bf16_t)p2; w[3] = (bf16_t)p3;
                pp[ki][qi] = w;
            }
        }

        // O^T += V^T P^T : paired-K packing, keys c*32.. covered per c
        #pragma unroll
        for (int c = 0; c < 2; c++) {
            bf16x8 pcat[4];
            #pragma unroll
            for (int qi = 0; qi < 4; qi++)
                pcat[qi] = __builtin_shufflevector(pp[2*c][qi], pp[2*c+1][qi],
                                                   0,1,2,3,4,5,6,7);
            #pragma unroll
            for (int di = 0; di < 4; di++) {
                bf16x4 v0 = *(const bf16x4*)&Vs[di*16 + l16][c*32 + 4*quad];
                bf16x4 v1 = *(const bf16x4*)&Vs[di*16 + l16][c*32 + 16 + 4*quad];
                bf16x8 vf = __builtin_shufflevector(v0, v1, 0,1,2,3,4,5,6,7);
                #pragma unroll
                for (int qi = 0; qi < 4; qi++)
                    acc[di][qi] = mfma16(vf, pcat[qi], acc[di][qi]);
            }
        }
    }

    // ---- epilogue: reduce l across quads (keys), normalize, transpose via
    // per-wave LDS slice, coalesced stores ----
    float inv[4];
    #pragma unroll
    for (int qi = 0; qi < 4; qi++) {
        float l = lpart[qi];
        l += __shfl_xor(l, 16);
        l += __shfl_xor(l, 32);
        inv[qi] = 1.0f / l;
    }

    const int qrd  = lane >> 2;          // 0..15: token row within qi-slice
    const int dch  = (lane & 3) * 16;    // d chunk for read-back
    #pragma unroll
    for (int qi = 0; qi < 4; qi++) {
        // write O^T slice: Po[q=l16][d=di*16+quad*4 .. +3] (b64, 2-way free)
        #pragma unroll
        for (int di = 0; di < 4; di++) {
            alignas(8) bf16_t w[4];
            #pragma unroll
            for (int r = 0; r < 4; r++)
                w[r] = (bf16_t)(acc[di][qi][r] * inv[qi]);
            *(uint2*)&Po[wave][l16][di*16 + quad*4] = *(uint2*)w;
        }
        asm volatile("s_waitcnt lgkmcnt(0)" ::: "memory");
        // read back token-major, store coalesced (4 lanes = 128B per token)
        uint4 o0 = *(const uint4*)&Po[wave][qrd][dch];
        uint4 o1 = *(const uint4*)&Po[wave][qrd][dch + 8];
        bf16_t* dst = aout + (size_t)(b*Sc + qt*256 + wave*64 + qi*16 + qrd)*Ec + h*Dc + dch;
        ((uint4*)dst)[0] = o0;
        ((uint4*)dst)[1] = o1;
        // WAR safe across qi: DS pipe executes a wave's ops in order
    }
}

extern "C" void kernel_launch(void* const* d_in, const int* in_sizes, int n_in,
                              void* d_out, int out_size, void* d_ws, size_t ws_size,
                              hipStream_t stream) {
    const float* query = (const float*)d_in[0];
    const float* W_qkv = (const float*)d_in[3];
    const float* b_qkv = (const float*)d_in[4];
    const float* W_out = (const float*)d_in[5];
    const float* b_out = (const float*)d_in[6];
    float* out = (float*)d_out;

    const size_t MT = (size_t)Bc * Sc;             // 8192 tokens
    char* ws = (char*)d_ws;
    size_t off = 0;
    bf16_t* qbf    = (bf16_t*)(ws + off); off += MT*Ec*2;            // query bf16 / attn out
    bf16_t* qkv_ws = (bf16_t*)(ws + off); off += MT*3*Ec*2;
    bf16_t* vt_ws  = (bf16_t*)(ws + off); off += MT*Ec*2;
    bf16_t* wqkv_t = (bf16_t*)(ws + off); off += (size_t)3*Ec*Ec*2;
    bf16_t* wout_t = (bf16_t*)(ws + off); off += (size_t)Ec*Ec*2;

    // 4 kernels (was 7): prep, gemm0(+tv fused), attn, gemm1
    prep<<<8192 + 768 + 256, 256, 0, stream>>>(
        query, qbf, W_qkv, wqkv_t, W_out, wout_t, (int)(MT*Ec/4));

    gemm3b<0><<<dim3(3*Ec/256, MT/128), 512, 0, stream>>>(
        qbf, wqkv_t, b_qkv, qkv_ws, (int)MT, 3*Ec, Ec, vt_ws);

    attn12<<<dim3(Bc*Hc, Sc/256), 256, 0, stream>>>(qkv_ws, vt_ws, qbf);

    gemm3b<1><<<dim3(Ec/256, MT/128), 512, 0, stream>>>(
        qbf, wout_t, b_out, out, (int)MT, Ec, Ec, nullptr);
}